// Round 8
// baseline (10346.216 us; speedup 1.0000x reference)
//
#include <hip/hip_runtime.h>
#include <hip/hip_bf16.h>

// Sheaf CNN on the fixed ring graph (offsets ±1..4 mod 4096, degree 8).
// Diagnostic-instrumented build, three fingerprint levels:
//   - pre-launch memsetAsync on d_out (0x3F bytes -> ~0.747 in bf16 AND f32)
//   - trivial 64-thread canary kernel writes ~1.0 to out[0..7]
//   - full pipeline kernel overwrites with the real result
//   - post-launch hipGetLastError -> 0x41 memset (~12.06) on failure
// Kernel handles BOTH input dtypes (bf16 / f32) via runtime probe.
// Single block, all intermediates in LDS, compile-time ring structure.

#define NN    4096
#define CHK   32            // chunk nodes
#define EXT   48            // chunk + 2*8 halo (A/B/G range, base c0-8)
#define PEXT  40            // chunk + 2*4 halo (p/s range,   base c0-4)

struct Smem {
    float As[EXT][64];
    float Bs[EXT][64];
    float Gs[EXT][64];
    float Hs[16][64];
    float ps[PEXT][8][2];
    float dinvs[PEXT][2];
    float facs[PEXT][2];
    float red[1024];
    float pooled[64];
    float hid[128];
};

template <bool F32>
static __device__ __forceinline__ float ldv(const void* p, int i) {
    if constexpr (F32) return ((const float*)p)[i];
    else return __bfloat162float(((const __hip_bfloat16*)p)[i]);
}

template <bool F32>
static __device__ void body(Smem& sm,
    const void* ef, const void* We, const void* be, const void* M1w,
    const void* M1b, const void* M2w, const void* M2b, const void* W1,
    const void* W2, const void* Wc1, const void* bc1, const void* Wc2,
    const void* bc2, void* out)
{
    const int t = threadIdx.x;
    const int c = t & 63;            // column / lane
    const int w = t >> 6;            // wave id (16 waves)
    const int a = (t >> 6) & 1;      // stalk dim for the Y phase
    const int ms = t >> 7;           // node sub-index for the Y phase

    const float m1b_c = ldv<F32>(M1b, c);
    const float m2w0  = ldv<F32>(M2w, c * 2 + 0);
    const float m2w1  = ldv<F32>(M2w, c * 2 + 1);
    const float m2b0  = ldv<F32>(M2b, 0);
    const float m2b1  = ldv<F32>(M2b, 1);
    // cs[a] = W1[0][a] + W1[1][a]  (W1 row-major (2,2))
    const float cs0 = ldv<F32>(W1, 0) + ldv<F32>(W1, 2);
    const float cs1 = ldv<F32>(W1, 1) + ldv<F32>(W1, 3);
    const float bec = ldv<F32>(be, c);

    float accY = 0.f;

    for (int ch = 0; ch < NN / CHK; ++ch) {
        const int c0 = ch * CHK;
        // ---- phase 1: per-node GEMVs over extended range [c0-8, c0+CHK+8) ----
        for (int pp = 0; pp < EXT / 16; ++pp) {
            const int q  = pp * 16 + w;               // local node in [0,EXT)
            const int gi = (c0 - 8 + q) & (NN - 1);   // global node (ring wrap)
            float aA = 0.f, aB = 0.f, aH = bec;
            #pragma unroll 2
            for (int k = 0; k < 128; ++k) {
                const float ev = ldv<F32>(ef, gi * 128 + k);
                aA += ev * ldv<F32>(M1w, k * 64 + c);          // M1w rows 0..127
                aB += ev * ldv<F32>(M1w, 8192 + k * 64 + c);   // M1w rows 128..255
                aH += ev * ldv<F32>(We, k * 64 + c);
            }
            sm.As[q][c] = aA;
            sm.Bs[q][c] = aB;
            sm.Hs[w][c] = fmaxf(aH, 0.f);
            __syncthreads();
            float aG = 0.f;
            #pragma unroll 2
            for (int k = 0; k < 64; ++k)
                aG += sm.Hs[w][k] * ldv<F32>(W2, k * 64 + c);
            sm.Gs[q][c] = aG;
            __syncthreads();                           // Hs reused next pass
        }
        // ---- phase 2: pair-MLP tail p(r,tt) for r in [c0-4, c0+CHK+4) ----
        for (int pi = w; pi < PEXT * 8; pi += 16) {
            const int r  = pi >> 3;                    // p-local node
            const int tt = pi & 7;                     // offset slot
            const int off = (tt < 4) ? (tt - 4) : (tt - 3);
            // A/B base is c0-8, p base is c0-4 -> shift +4
            const float h = fmaxf(sm.As[r + 4][c] + sm.Bs[r + 4 + off][c] + m1b_c, 0.f);
            float q0 = h * m2w0, q1 = h * m2w1;
            #pragma unroll
            for (int d2 = 32; d2; d2 >>= 1) {
                q0 += __shfl_xor(q0, d2);
                q1 += __shfl_xor(q1, d2);
            }
            if (c == 0) {
                sm.ps[r][tt][0] = q0 + m2b0;
                sm.ps[r][tt][1] = q1 + m2b1;
            }
        }
        __syncthreads();
        // ---- phase 3: s, dinv, fac ----
        if (t < PEXT * 2) {
            const int r = t >> 1, aa = t & 1;
            float s = 0.f;
            #pragma unroll
            for (int tt = 0; tt < 8; ++tt) { const float p = sm.ps[r][tt][aa]; s += p * p; }
            const float dv = 1.f / sqrtf(fmaxf(s + 1e-5f, 1e-6f));
            sm.dinvs[r][aa] = dv;
            sm.facs[r][aa]  = 1.f - dv * dv * s;
        }
        __syncthreads();
        // ---- phase 4: Y rows for the 32 chunk nodes + pooled accumulation ----
        const float csa = a ? cs1 : cs0;
        #pragma unroll
        for (int it = 0; it < 4; ++it) {
            const int m = it * 8 + ms;   // node local in chunk [0,32)
            const int r = m + 4;         // p-local
            const int g = m + 8;         // A/B/G-local
            const float di = sm.dinvs[r][a];
            float v = sm.facs[r][a] * sm.Gs[g][c];
            #pragma unroll
            for (int tt = 0; tt < 8; ++tt) {
                const int off = (tt < 4) ? (tt - 4) : (tt - 3);
                // p_rev = p(j -> i) lives at slot 7-tt of node j
                v += di * sm.ps[r + off][7 - tt][a] * sm.ps[r][tt][a]
                        * sm.dinvs[r + off][a] * sm.Gs[g + off][c];
            }
            const float x = csa * v;
            accY += (x > 0.f) ? x : expm1f(x);
        }
        __syncthreads();   // protect LDS reuse next chunk
    }

    // ---- mean pool over all 8192 Y rows ----
    sm.red[t] = accY;
    __syncthreads();
    if (t < 64) {
        float s = 0.f;
        #pragma unroll
        for (int g2 = 0; g2 < 16; ++g2) s += sm.red[(g2 << 6) + t];
        sm.pooled[t] = s * (1.f / 8192.f);
    }
    __syncthreads();
    // ---- classifier ----
    if (t < 128) {
        float acc = ldv<F32>(bc1, t);
        #pragma unroll 8
        for (int k = 0; k < 64; ++k) acc += sm.pooled[k] * ldv<F32>(Wc1, k * 128 + t);
        sm.hid[t] = fmaxf(acc, 0.f);
    }
    __syncthreads();
    if (t < 8) {
        float acc = ldv<F32>(bc2, t);
        #pragma unroll 8
        for (int k = 0; k < 128; ++k) acc += sm.hid[k] * ldv<F32>(Wc2, k * 8 + t);
        if constexpr (F32) ((float*)out)[t] = acc;
        else ((__hip_bfloat16*)out)[t] = __float2bfloat16(acc);
    }
}

// Trivial canary: if ANY kernel can execute, out[0..7] become ~1.0
// (pattern 0x3F80 per 16-bit half: bf16 1.0 exactly; f32 0x3F803F80 ~ 1.0020).
__global__ __launch_bounds__(64) void sheaf_canary(unsigned short* out)
{
    if (threadIdx.x < 8) out[threadIdx.x] = 0x3F80;
}

__global__ __launch_bounds__(1024) void SheafConvolutionalNetwork_81698867905240_kernel(
    const void* ef, const void* We, const void* be, const void* M1w,
    const void* M1b, const void* M2w, const void* M2b, const void* W1,
    const void* W2, const void* Wc1, const void* bc1, const void* Wc2,
    const void* bc2, void* out)
{
    __shared__ Smem sm;
    __shared__ int flag;
    const int t = threadIdx.x;
    if (t == 0) flag = 0;
    __syncthreads();
    // dtype probe: if buffers are f32, even bf16-slot reinterpretations have
    // uniformly random exponents -> huge/NaN values appear with certainty.
    {
        const __hip_bfloat16* efh = (const __hip_bfloat16*)ef;
        bool big = false;
        #pragma unroll
        for (int k = 0; k < 8; ++k) {
            const float v = __bfloat162float(efh[t * 8 + k]);   // idx < 8192
            big |= !(fabsf(v) < 1e4f);                          // catches NaN
        }
        if (big) atomicOr(&flag, 1);
    }
    __syncthreads();
    if (flag)
        body<true >(sm, ef, We, be, M1w, M1b, M2w, M2b, W1, W2, Wc1, bc1, Wc2, bc2, out);
    else
        body<false>(sm, ef, We, be, M1w, M1b, M2w, M2b, W1, W2, Wc1, bc1, Wc2, bc2, out);
}

extern "C" void kernel_launch(void* const* d_in, const int* in_sizes, int n_in,
                              void* d_out, int out_size, void* d_ws, size_t ws_size,
                              hipStream_t stream)
{
    (void)in_sizes; (void)n_in; (void)d_ws; (void)ws_size; (void)out_size;

    // Fingerprint 1: stream memset marks d_out (~0.747 in both dtypes).
    (void)hipMemsetAsync(d_out, 0x3F, 16, stream);

    // Fingerprint 2: trivial canary kernel (~1.0 in both dtypes).
    sheaf_canary<<<dim3(1), dim3(64), 0, stream>>>((unsigned short*)d_out);

    (void)hipGetLastError();   // clear any stale error
    // Real pipeline: overwrites with the correct logits.
    SheafConvolutionalNetwork_81698867905240_kernel<<<dim3(1), dim3(1024), 0, stream>>>(
        d_in[0],  // edge_features
        d_in[1],  // We
        d_in[2],  // be
        d_in[3],  // M1w
        d_in[4],  // M1b
        d_in[5],  // M2w
        d_in[6],  // M2b
        d_in[7],  // W1
        d_in[8],  // W2
        d_in[9],  // Wc1
        d_in[10], // bc1
        d_in[11], // Wc2
        d_in[12], // bc2
        d_out);

    // Fingerprint 3: explicit launch-error marker (~12.06 in both dtypes).
    if (hipGetLastError() != hipSuccess)
        (void)hipMemsetAsync(d_out, 0x41, 16, stream);
}

// Round 16
// 10345.300 us; speedup vs baseline: 1.0001x; 1.0001x over previous
//
#include <hip/hip_runtime.h>
#include <hip/hip_bf16.h>

// Sheaf CNN on the fixed ring graph (offsets ±1..4 mod 4096, degree 8).
// Diagnostic-instrumented build, three fingerprint levels:
//   - pre-launch memsetAsync on d_out (0x3F bytes -> ~0.747 in bf16 AND f32)
//   - trivial 64-thread canary kernel writes ~1.0 to out[0..7]
//   - full pipeline kernel overwrites with the real result
//   - post-launch hipGetLastError -> 0x41 memset (~12.06) on failure
// Kernel handles BOTH input dtypes (bf16 / f32) via runtime probe.
// Single block, all intermediates in LDS, compile-time ring structure.

#define NN    4096
#define CHK   32            // chunk nodes
#define EXT   48            // chunk + 2*8 halo (A/B/G range, base c0-8)
#define PEXT  40            // chunk + 2*4 halo (p/s range,   base c0-4)

struct Smem {
    float As[EXT][64];
    float Bs[EXT][64];
    float Gs[EXT][64];
    float Hs[16][64];
    float ps[PEXT][8][2];
    float dinvs[PEXT][2];
    float facs[PEXT][2];
    float red[1024];
    float pooled[64];
    float hid[128];
};

template <bool F32>
static __device__ __forceinline__ float ldv(const void* p, int i) {
    if constexpr (F32) return ((const float*)p)[i];
    else return __bfloat162float(((const __hip_bfloat16*)p)[i]);
}

template <bool F32>
static __device__ void body(Smem& sm,
    const void* ef, const void* We, const void* be, const void* M1w,
    const void* M1b, const void* M2w, const void* M2b, const void* W1,
    const void* W2, const void* Wc1, const void* bc1, const void* Wc2,
    const void* bc2, void* out)
{
    const int t = threadIdx.x;
    const int c = t & 63;            // column / lane
    const int w = t >> 6;            // wave id (16 waves)
    const int a = (t >> 6) & 1;      // stalk dim for the Y phase
    const int ms = t >> 7;           // node sub-index for the Y phase

    const float m1b_c = ldv<F32>(M1b, c);
    const float m2w0  = ldv<F32>(M2w, c * 2 + 0);
    const float m2w1  = ldv<F32>(M2w, c * 2 + 1);
    const float m2b0  = ldv<F32>(M2b, 0);
    const float m2b1  = ldv<F32>(M2b, 1);
    // cs[a] = W1[0][a] + W1[1][a]  (W1 row-major (2,2))
    const float cs0 = ldv<F32>(W1, 0) + ldv<F32>(W1, 2);
    const float cs1 = ldv<F32>(W1, 1) + ldv<F32>(W1, 3);
    const float bec = ldv<F32>(be, c);

    float accY = 0.f;

    for (int ch = 0; ch < NN / CHK; ++ch) {
        const int c0 = ch * CHK;
        // ---- phase 1: per-node GEMVs over extended range [c0-8, c0+CHK+8) ----
        for (int pp = 0; pp < EXT / 16; ++pp) {
            const int q  = pp * 16 + w;               // local node in [0,EXT)
            const int gi = (c0 - 8 + q) & (NN - 1);   // global node (ring wrap)
            float aA = 0.f, aB = 0.f, aH = bec;
            #pragma unroll 2
            for (int k = 0; k < 128; ++k) {
                const float ev = ldv<F32>(ef, gi * 128 + k);
                aA += ev * ldv<F32>(M1w, k * 64 + c);          // M1w rows 0..127
                aB += ev * ldv<F32>(M1w, 8192 + k * 64 + c);   // M1w rows 128..255
                aH += ev * ldv<F32>(We, k * 64 + c);
            }
            sm.As[q][c] = aA;
            sm.Bs[q][c] = aB;
            sm.Hs[w][c] = fmaxf(aH, 0.f);
            __syncthreads();
            float aG = 0.f;
            #pragma unroll 2
            for (int k = 0; k < 64; ++k)
                aG += sm.Hs[w][k] * ldv<F32>(W2, k * 64 + c);
            sm.Gs[q][c] = aG;
            __syncthreads();                           // Hs reused next pass
        }
        // ---- phase 2: pair-MLP tail p(r,tt) for r in [c0-4, c0+CHK+4) ----
        for (int pi = w; pi < PEXT * 8; pi += 16) {
            const int r  = pi >> 3;                    // p-local node
            const int tt = pi & 7;                     // offset slot
            const int off = (tt < 4) ? (tt - 4) : (tt - 3);
            // A/B base is c0-8, p base is c0-4 -> shift +4
            const float h = fmaxf(sm.As[r + 4][c] + sm.Bs[r + 4 + off][c] + m1b_c, 0.f);
            float q0 = h * m2w0, q1 = h * m2w1;
            #pragma unroll
            for (int d2 = 32; d2; d2 >>= 1) {
                q0 += __shfl_xor(q0, d2);
                q1 += __shfl_xor(q1, d2);
            }
            if (c == 0) {
                sm.ps[r][tt][0] = q0 + m2b0;
                sm.ps[r][tt][1] = q1 + m2b1;
            }
        }
        __syncthreads();
        // ---- phase 3: s, dinv, fac ----
        if (t < PEXT * 2) {
            const int r = t >> 1, aa = t & 1;
            float s = 0.f;
            #pragma unroll
            for (int tt = 0; tt < 8; ++tt) { const float p = sm.ps[r][tt][aa]; s += p * p; }
            const float dv = 1.f / sqrtf(fmaxf(s + 1e-5f, 1e-6f));
            sm.dinvs[r][aa] = dv;
            sm.facs[r][aa]  = 1.f - dv * dv * s;
        }
        __syncthreads();
        // ---- phase 4: Y rows for the 32 chunk nodes + pooled accumulation ----
        const float csa = a ? cs1 : cs0;
        #pragma unroll
        for (int it = 0; it < 4; ++it) {
            const int m = it * 8 + ms;   // node local in chunk [0,32)
            const int r = m + 4;         // p-local
            const int g = m + 8;         // A/B/G-local
            const float di = sm.dinvs[r][a];
            float v = sm.facs[r][a] * sm.Gs[g][c];
            #pragma unroll
            for (int tt = 0; tt < 8; ++tt) {
                const int off = (tt < 4) ? (tt - 4) : (tt - 3);
                // p_rev = p(j -> i) lives at slot 7-tt of node j
                v += di * sm.ps[r + off][7 - tt][a] * sm.ps[r][tt][a]
                        * sm.dinvs[r + off][a] * sm.Gs[g + off][c];
            }
            const float x = csa * v;
            accY += (x > 0.f) ? x : expm1f(x);
        }
        __syncthreads();   // protect LDS reuse next chunk
    }

    // ---- mean pool over all 8192 Y rows ----
    sm.red[t] = accY;
    __syncthreads();
    if (t < 64) {
        float s = 0.f;
        #pragma unroll
        for (int g2 = 0; g2 < 16; ++g2) s += sm.red[(g2 << 6) + t];
        sm.pooled[t] = s * (1.f / 8192.f);
    }
    __syncthreads();
    // ---- classifier ----
    if (t < 128) {
        float acc = ldv<F32>(bc1, t);
        #pragma unroll 8
        for (int k = 0; k < 64; ++k) acc += sm.pooled[k] * ldv<F32>(Wc1, k * 128 + t);
        sm.hid[t] = fmaxf(acc, 0.f);
    }
    __syncthreads();
    if (t < 8) {
        float acc = ldv<F32>(bc2, t);
        #pragma unroll 8
        for (int k = 0; k < 128; ++k) acc += sm.hid[k] * ldv<F32>(Wc2, k * 8 + t);
        if constexpr (F32) ((float*)out)[t] = acc;
        else ((__hip_bfloat16*)out)[t] = __float2bfloat16(acc);
    }
}

// Trivial canary: if ANY kernel can execute, out[0..7] become ~1.0
// (pattern 0x3F80 per 16-bit half: bf16 1.0 exactly; f32 0x3F803F80 ~ 1.0020).
__global__ __launch_bounds__(64) void sheaf_canary(unsigned short* out)
{
    if (threadIdx.x < 8) out[threadIdx.x] = 0x3F80;
}

__global__ __launch_bounds__(1024) void SheafConvolutionalNetwork_81698867905240_kernel(
    const void* ef, const void* We, const void* be, const void* M1w,
    const void* M1b, const void* M2w, const void* M2b, const void* W1,
    const void* W2, const void* Wc1, const void* bc1, const void* Wc2,
    const void* bc2, void* out)
{
    __shared__ Smem sm;
    __shared__ int flag;
    const int t = threadIdx.x;
    if (t == 0) flag = 0;
    __syncthreads();
    // dtype probe: if buffers are f32, even bf16-slot reinterpretations have
    // uniformly random exponents -> huge/NaN values appear with certainty.
    {
        const __hip_bfloat16* efh = (const __hip_bfloat16*)ef;
        bool big = false;
        #pragma unroll
        for (int k = 0; k < 8; ++k) {
            const float v = __bfloat162float(efh[t * 8 + k]);   // idx < 8192
            big |= !(fabsf(v) < 1e4f);                          // catches NaN
        }
        if (big) atomicOr(&flag, 1);
    }
    __syncthreads();
    if (flag)
        body<true >(sm, ef, We, be, M1w, M1b, M2w, M2b, W1, W2, Wc1, bc1, Wc2, bc2, out);
    else
        body<false>(sm, ef, We, be, M1w, M1b, M2w, M2b, W1, W2, Wc1, bc1, Wc2, bc2, out);
}

extern "C" void kernel_launch(void* const* d_in, const int* in_sizes, int n_in,
                              void* d_out, int out_size, void* d_ws, size_t ws_size,
                              hipStream_t stream)
{
    (void)in_sizes; (void)n_in; (void)d_ws; (void)ws_size; (void)out_size;

    // Fingerprint 1: stream memset marks d_out (~0.747 in both dtypes).
    (void)hipMemsetAsync(d_out, 0x3F, 16, stream);

    // Fingerprint 2: trivial canary kernel (~1.0 in both dtypes).
    sheaf_canary<<<dim3(1), dim3(64), 0, stream>>>((unsigned short*)d_out);

    (void)hipGetLastError();   // clear any stale error
    // Real pipeline: overwrites with the correct logits.
    SheafConvolutionalNetwork_81698867905240_kernel<<<dim3(1), dim3(1024), 0, stream>>>(
        d_in[0],  // edge_features
        d_in[1],  // We
        d_in[2],  // be
        d_in[3],  // M1w
        d_in[4],  // M1b
        d_in[5],  // M2w
        d_in[6],  // M2b
        d_in[7],  // W1
        d_in[8],  // W2
        d_in[9],  // Wc1
        d_in[10], // bc1
        d_in[11], // Wc2
        d_in[12], // bc2
        d_out);

    // Fingerprint 3: explicit launch-error marker (~12.06 in both dtypes).
    if (hipGetLastError() != hipSuccess)
        (void)hipMemsetAsync(d_out, 0x41, 16, stream);
}

// Round 17
// 112.140 us; speedup vs baseline: 92.2620x; 92.2538x over previous
//
#include <hip/hip_runtime.h>
#include <hip/hip_bf16.h>

// Sheaf CNN on the fixed ring graph (offsets ±1..4 mod 4096, degree 8).
// Minimal-delta parallelization of the R8/R16-proven build:
//   - same includes, Smem, templates, canary, main-kernel signature
//   - chunk loop now strided by gridDim; grid=128 -> one 32-node chunk/block
//   - multi-block: main kernel's out param receives d_ws; each block writes
//     its 64-float pooled partial there; small finalize kernel reduces in
//     fixed order + classifier -> d_out
//   - ws-guard: if d_ws too small, identical kernel runs <<<1,1024>>> with
//     out=d_out (exact R8 behavior, slow but correct)
// Fingerprints retained: 0x3F pre-memset, canary ~1.0, 0x41 on launch error.

#define NN    4096
#define CHK   32            // chunk nodes
#define EXT   48            // chunk + 2*8 halo (A/B/G range, base c0-8)
#define PEXT  40            // chunk + 2*4 halo (p/s range,   base c0-4)
#define NGRID 128           // NN/CHK chunks, one per block
#define WS_NEED (NGRID * 64u * 4u)

struct Smem {
    float As[EXT][64];
    float Bs[EXT][64];
    float Gs[EXT][64];
    float Hs[16][64];
    float ps[PEXT][8][2];
    float dinvs[PEXT][2];
    float facs[PEXT][2];
    float red[1024];
    float pooled[64];
    float hid[128];
};

template <bool F32>
static __device__ __forceinline__ float ldv(const void* p, int i) {
    if constexpr (F32) return ((const float*)p)[i];
    else return __bfloat162float(((const __hip_bfloat16*)p)[i]);
}

static __device__ __forceinline__ float ldr(const void* p, int i, bool f32) {
    if (f32) return ((const float*)p)[i];
    return __bfloat162float(((const __hip_bfloat16*)p)[i]);
}

template <bool F32>
static __device__ void body(Smem& sm,
    const void* ef, const void* We, const void* be, const void* M1w,
    const void* M1b, const void* M2w, const void* M2b, const void* W1,
    const void* W2, const void* Wc1, const void* bc1, const void* Wc2,
    const void* bc2, void* out)
{
    const int t = threadIdx.x;
    const int c = t & 63;            // column / lane
    const int w = t >> 6;            // wave id (16 waves)
    const int a = (t >> 6) & 1;      // stalk dim for the Y phase
    const int ms = t >> 7;           // node sub-index for the Y phase

    const float m1b_c = ldv<F32>(M1b, c);
    const float m2w0  = ldv<F32>(M2w, c * 2 + 0);
    const float m2w1  = ldv<F32>(M2w, c * 2 + 1);
    const float m2b0  = ldv<F32>(M2b, 0);
    const float m2b1  = ldv<F32>(M2b, 1);
    // cs[a] = W1[0][a] + W1[1][a]  (W1 row-major (2,2))
    const float cs0 = ldv<F32>(W1, 0) + ldv<F32>(W1, 2);
    const float cs1 = ldv<F32>(W1, 1) + ldv<F32>(W1, 3);
    const float bec = ldv<F32>(be, c);

    float accY = 0.f;

    for (int ch = blockIdx.x; ch < NN / CHK; ch += gridDim.x) {
        const int c0 = ch * CHK;
        // ---- phase 1: per-node GEMVs over extended range [c0-8, c0+CHK+8) ----
        for (int pp = 0; pp < EXT / 16; ++pp) {
            const int q  = pp * 16 + w;               // local node in [0,EXT)
            const int gi = (c0 - 8 + q) & (NN - 1);   // global node (ring wrap)
            float aA = 0.f, aB = 0.f, aH = bec;
            #pragma unroll 2
            for (int k = 0; k < 128; ++k) {
                const float ev = ldv<F32>(ef, gi * 128 + k);
                aA += ev * ldv<F32>(M1w, k * 64 + c);          // M1w rows 0..127
                aB += ev * ldv<F32>(M1w, 8192 + k * 64 + c);   // M1w rows 128..255
                aH += ev * ldv<F32>(We, k * 64 + c);
            }
            sm.As[q][c] = aA;
            sm.Bs[q][c] = aB;
            sm.Hs[w][c] = fmaxf(aH, 0.f);
            __syncthreads();
            float aG = 0.f;
            #pragma unroll 2
            for (int k = 0; k < 64; ++k)
                aG += sm.Hs[w][k] * ldv<F32>(W2, k * 64 + c);
            sm.Gs[q][c] = aG;
            __syncthreads();                           // Hs reused next pass
        }
        // ---- phase 2: pair-MLP tail p(r,tt) for r in [c0-4, c0+CHK+4) ----
        for (int pi = w; pi < PEXT * 8; pi += 16) {
            const int r  = pi >> 3;                    // p-local node
            const int tt = pi & 7;                     // offset slot
            const int off = (tt < 4) ? (tt - 4) : (tt - 3);
            // A/B base is c0-8, p base is c0-4 -> shift +4
            const float h = fmaxf(sm.As[r + 4][c] + sm.Bs[r + 4 + off][c] + m1b_c, 0.f);
            float q0 = h * m2w0, q1 = h * m2w1;
            #pragma unroll
            for (int d2 = 32; d2; d2 >>= 1) {
                q0 += __shfl_xor(q0, d2);
                q1 += __shfl_xor(q1, d2);
            }
            if (c == 0) {
                sm.ps[r][tt][0] = q0 + m2b0;
                sm.ps[r][tt][1] = q1 + m2b1;
            }
        }
        __syncthreads();
        // ---- phase 3: s, dinv, fac ----
        if (t < PEXT * 2) {
            const int r = t >> 1, aa = t & 1;
            float s = 0.f;
            #pragma unroll
            for (int tt = 0; tt < 8; ++tt) { const float p = sm.ps[r][tt][aa]; s += p * p; }
            const float dv = 1.f / sqrtf(fmaxf(s + 1e-5f, 1e-6f));
            sm.dinvs[r][aa] = dv;
            sm.facs[r][aa]  = 1.f - dv * dv * s;
        }
        __syncthreads();
        // ---- phase 4: Y rows for the 32 chunk nodes + pooled accumulation ----
        const float csa = a ? cs1 : cs0;
        #pragma unroll
        for (int it = 0; it < 4; ++it) {
            const int m = it * 8 + ms;   // node local in chunk [0,32)
            const int r = m + 4;         // p-local
            const int g = m + 8;         // A/B/G-local
            const float di = sm.dinvs[r][a];
            float v = sm.facs[r][a] * sm.Gs[g][c];
            #pragma unroll
            for (int tt = 0; tt < 8; ++tt) {
                const int off = (tt < 4) ? (tt - 4) : (tt - 3);
                // p_rev = p(j -> i) lives at slot 7-tt of node j
                v += di * sm.ps[r + off][7 - tt][a] * sm.ps[r][tt][a]
                        * sm.dinvs[r + off][a] * sm.Gs[g + off][c];
            }
            const float x = csa * v;
            accY += (x > 0.f) ? x : expm1f(x);
        }
        __syncthreads();   // protect LDS reuse next chunk
    }

    // ---- pooled reduce ----
    sm.red[t] = accY;
    __syncthreads();

    if (gridDim.x > 1) {
        // multi-block: write this block's 64-float partial to out (= d_ws)
        if (t < 64) {
            float s = 0.f;
            #pragma unroll
            for (int g2 = 0; g2 < 16; ++g2) s += sm.red[(g2 << 6) + t];
            ((float*)out)[blockIdx.x * 64 + t] = s;
        }
        return;
    }

    // single-block: full tail (R8-proven path), out = d_out
    if (t < 64) {
        float s = 0.f;
        #pragma unroll
        for (int g2 = 0; g2 < 16; ++g2) s += sm.red[(g2 << 6) + t];
        sm.pooled[t] = s * (1.f / 8192.f);
    }
    __syncthreads();
    if (t < 128) {
        float acc = ldv<F32>(bc1, t);
        #pragma unroll 8
        for (int k = 0; k < 64; ++k) acc += sm.pooled[k] * ldv<F32>(Wc1, k * 128 + t);
        sm.hid[t] = fmaxf(acc, 0.f);
    }
    __syncthreads();
    if (t < 8) {
        float acc = ldv<F32>(bc2, t);
        #pragma unroll 8
        for (int k = 0; k < 128; ++k) acc += sm.hid[k] * ldv<F32>(Wc2, k * 8 + t);
        if constexpr (F32) ((float*)out)[t] = acc;
        else ((__hip_bfloat16*)out)[t] = __float2bfloat16(acc);
    }
}

// Trivial canary: if ANY kernel can execute, out[0..7] become ~1.0.
__global__ __launch_bounds__(64) void sheaf_canary(unsigned short* out)
{
    if (threadIdx.x < 8) out[threadIdx.x] = 0x3F80;
}

// Finalize: fixed-order reduce of NGRID partials + classifier -> out.
__global__ __launch_bounds__(256) void sheaf_finalize(
    const void* ef, const void* Wc1, const void* bc1, const void* Wc2,
    const void* bc2, const float* partials, void* out)
{
    __shared__ float red[256];
    __shared__ float pooled[64];
    __shared__ float hid[128];
    __shared__ int flag;
    const int t = threadIdx.x;
    if (t == 0) flag = 0;
    __syncthreads();
    {   // same dtype probe as the main kernel (idx < 2048, in-bounds)
        const __hip_bfloat16* efh = (const __hip_bfloat16*)ef;
        bool big = false;
        #pragma unroll
        for (int k = 0; k < 8; ++k) {
            const float v = __bfloat162float(efh[t * 8 + k]);
            big |= !(fabsf(v) < 1e4f);
        }
        if (big) atomicOr(&flag, 1);
    }
    __syncthreads();
    const bool f32 = (flag != 0);

    const int h = t & 63, g = t >> 6;      // 4 groups of 64
    float s = 0.f;
    for (int b = g; b < NGRID; b += 4) s += partials[b * 64 + h];
    red[t] = s;
    __syncthreads();
    if (t < 64)
        pooled[t] = (red[t] + red[t + 64] + red[t + 128] + red[t + 192]) * (1.f / 8192.f);
    __syncthreads();
    if (t < 128) {
        float acc = ldr(bc1, t, f32);
        #pragma unroll 8
        for (int k = 0; k < 64; ++k) acc += pooled[k] * ldr(Wc1, k * 128 + t, f32);
        hid[t] = fmaxf(acc, 0.f);
    }
    __syncthreads();
    if (t < 8) {
        float acc = ldr(bc2, t, f32);
        #pragma unroll 8
        for (int k = 0; k < 128; ++k) acc += hid[k] * ldr(Wc2, k * 8 + t, f32);
        if (f32) ((float*)out)[t] = acc;
        else ((__hip_bfloat16*)out)[t] = __float2bfloat16(acc);
    }
}

__global__ __launch_bounds__(1024) void SheafConvolutionalNetwork_81698867905240_kernel(
    const void* ef, const void* We, const void* be, const void* M1w,
    const void* M1b, const void* M2w, const void* M2b, const void* W1,
    const void* W2, const void* Wc1, const void* bc1, const void* Wc2,
    const void* bc2, void* out)
{
    __shared__ Smem sm;
    __shared__ int flag;
    const int t = threadIdx.x;
    if (t == 0) flag = 0;
    __syncthreads();
    // dtype probe: if buffers are f32, even bf16-slot reinterpretations have
    // uniformly random exponents -> huge/NaN values appear with certainty.
    {
        const __hip_bfloat16* efh = (const __hip_bfloat16*)ef;
        bool big = false;
        #pragma unroll
        for (int k = 0; k < 8; ++k) {
            const float v = __bfloat162float(efh[t * 8 + k]);   // idx < 8192
            big |= !(fabsf(v) < 1e4f);                          // catches NaN
        }
        if (big) atomicOr(&flag, 1);
    }
    __syncthreads();
    if (flag)
        body<true >(sm, ef, We, be, M1w, M1b, M2w, M2b, W1, W2, Wc1, bc1, Wc2, bc2, out);
    else
        body<false>(sm, ef, We, be, M1w, M1b, M2w, M2b, W1, W2, Wc1, bc1, Wc2, bc2, out);
}

extern "C" void kernel_launch(void* const* d_in, const int* in_sizes, int n_in,
                              void* d_out, int out_size, void* d_ws, size_t ws_size,
                              hipStream_t stream)
{
    (void)in_sizes; (void)n_in; (void)out_size;

    const bool big = (d_ws != nullptr) && (ws_size >= (size_t)WS_NEED);

    // Fingerprint 1: stream memset marks d_out (~0.747 in both dtypes).
    (void)hipMemsetAsync(d_out, 0x3F, 16, stream);

    // Fingerprint 2: trivial canary kernel (~1.0 in both dtypes).
    sheaf_canary<<<dim3(1), dim3(64), 0, stream>>>((unsigned short*)d_out);

    (void)hipGetLastError();   // clear any stale error
    if (big) {
        // multi-block: out param := d_ws (partials), then finalize -> d_out
        SheafConvolutionalNetwork_81698867905240_kernel<<<dim3(NGRID), dim3(1024), 0, stream>>>(
            d_in[0], d_in[1], d_in[2], d_in[3], d_in[4], d_in[5], d_in[6],
            d_in[7], d_in[8], d_in[9], d_in[10], d_in[11], d_in[12], d_ws);
        sheaf_finalize<<<dim3(1), dim3(256), 0, stream>>>(
            d_in[0], d_in[9], d_in[10], d_in[11], d_in[12],
            (const float*)d_ws, d_out);
    } else {
        // fallback: exact R8 behavior (single block, direct to d_out)
        SheafConvolutionalNetwork_81698867905240_kernel<<<dim3(1), dim3(1024), 0, stream>>>(
            d_in[0], d_in[1], d_in[2], d_in[3], d_in[4], d_in[5], d_in[6],
            d_in[7], d_in[8], d_in[9], d_in[10], d_in[11], d_in[12], d_out);
    }

    // Fingerprint 3: explicit launch-error marker (~12.06 in both dtypes).
    if (hipGetLastError() != hipSuccess)
        (void)hipMemsetAsync(d_out, 0x41, 16, stream);
}

// Round 19
// 66.017 us; speedup vs baseline: 156.7198x; 1.6986x over previous
//
#include <hip/hip_runtime.h>
#include <hip/hip_bf16.h>

// Sheaf CNN on the fixed ring graph (offsets ±1..4 mod 4096, degree 8).
// 3-kernel pipeline (d_ws handoff proven in R17):
//   K1: A,B,G for all nodes, no halo redundancy, ef in LDS, unroll 8 -> d_ws
//   K2: phases 2-4 per 16-node chunk, halo rows read from d_ws; partials
//   K3: fixed-order reduce + classifier -> d_out
// Fallbacks (proven byte-patterns): ws<3.2MB -> R17 128-block halo kernel;
// ws<32KB -> single-block R8 path. Canary + fingerprints retained.

#define NN    4096
#define CHK   32            // R17 fallback: chunk nodes
#define EXT   48            // R17 fallback: chunk + 2*8 halo
#define PEXT  40            // R17 fallback: chunk + 2*4 halo
#define NGRID 128           // R17 fallback grid
#define WS_R17 (NGRID * 64u * 4u)

#define NBLK2 256           // pipeline grid (16 nodes/block)
#define PEXT2 24            // 16 + 2*4
#define WS_PIPE ((3u * NN * 64u + NBLK2 * 64u) * 4u)

struct Smem {
    float As[EXT][64];
    float Bs[EXT][64];
    float Gs[EXT][64];
    float Hs[16][64];
    float ps[PEXT][8][2];
    float dinvs[PEXT][2];
    float facs[PEXT][2];
    float red[1024];
    float pooled[64];
    float hid[128];
};

struct SmemK2 {
    float As[PEXT2][64];      // A rows [base-4, base+20)
    float Bs[32][64];         // B rows [base-8, base+24)
    float Gs[32][64];         // G rows [base-8, base+24)
    float ps[PEXT2][8][2];
    float dinvs[PEXT2][2];
    float facs[PEXT2][2];
    float red[1024];
};

template <bool F32>
static __device__ __forceinline__ float ldv(const void* p, int i) {
    if constexpr (F32) return ((const float*)p)[i];
    else return __bfloat162float(((const __hip_bfloat16*)p)[i]);
}

static __device__ __forceinline__ float ldr(const void* p, int i, bool f32) {
    if (f32) return ((const float*)p)[i];
    return __bfloat162float(((const __hip_bfloat16*)p)[i]);
}

// ---------- R8/R17-proven halo body (fallback paths) ----------
template <bool F32>
static __device__ void body(Smem& sm,
    const void* ef, const void* We, const void* be, const void* M1w,
    const void* M1b, const void* M2w, const void* M2b, const void* W1,
    const void* W2, const void* Wc1, const void* bc1, const void* Wc2,
    const void* bc2, void* out)
{
    const int t = threadIdx.x;
    const int c = t & 63;
    const int w = t >> 6;
    const int a = (t >> 6) & 1;
    const int ms = t >> 7;

    const float m1b_c = ldv<F32>(M1b, c);
    const float m2w0  = ldv<F32>(M2w, c * 2 + 0);
    const float m2w1  = ldv<F32>(M2w, c * 2 + 1);
    const float m2b0  = ldv<F32>(M2b, 0);
    const float m2b1  = ldv<F32>(M2b, 1);
    const float cs0 = ldv<F32>(W1, 0) + ldv<F32>(W1, 2);
    const float cs1 = ldv<F32>(W1, 1) + ldv<F32>(W1, 3);
    const float bec = ldv<F32>(be, c);

    float accY = 0.f;

    for (int ch = blockIdx.x; ch < NN / CHK; ch += gridDim.x) {
        const int c0 = ch * CHK;
        for (int pp = 0; pp < EXT / 16; ++pp) {
            const int q  = pp * 16 + w;
            const int gi = (c0 - 8 + q) & (NN - 1);
            float aA = 0.f, aB = 0.f, aH = bec;
            #pragma unroll 2
            for (int k = 0; k < 128; ++k) {
                const float ev = ldv<F32>(ef, gi * 128 + k);
                aA += ev * ldv<F32>(M1w, k * 64 + c);
                aB += ev * ldv<F32>(M1w, 8192 + k * 64 + c);
                aH += ev * ldv<F32>(We, k * 64 + c);
            }
            sm.As[q][c] = aA;
            sm.Bs[q][c] = aB;
            sm.Hs[w][c] = fmaxf(aH, 0.f);
            __syncthreads();
            float aG = 0.f;
            #pragma unroll 2
            for (int k = 0; k < 64; ++k)
                aG += sm.Hs[w][k] * ldv<F32>(W2, k * 64 + c);
            sm.Gs[q][c] = aG;
            __syncthreads();
        }
        for (int pi = w; pi < PEXT * 8; pi += 16) {
            const int r  = pi >> 3;
            const int tt = pi & 7;
            const int off = (tt < 4) ? (tt - 4) : (tt - 3);
            const float h = fmaxf(sm.As[r + 4][c] + sm.Bs[r + 4 + off][c] + m1b_c, 0.f);
            float q0 = h * m2w0, q1 = h * m2w1;
            #pragma unroll
            for (int d2 = 32; d2; d2 >>= 1) {
                q0 += __shfl_xor(q0, d2);
                q1 += __shfl_xor(q1, d2);
            }
            if (c == 0) {
                sm.ps[r][tt][0] = q0 + m2b0;
                sm.ps[r][tt][1] = q1 + m2b1;
            }
        }
        __syncthreads();
        if (t < PEXT * 2) {
            const int r = t >> 1, aa = t & 1;
            float s = 0.f;
            #pragma unroll
            for (int tt = 0; tt < 8; ++tt) { const float p = sm.ps[r][tt][aa]; s += p * p; }
            const float dv = 1.f / sqrtf(fmaxf(s + 1e-5f, 1e-6f));
            sm.dinvs[r][aa] = dv;
            sm.facs[r][aa]  = 1.f - dv * dv * s;
        }
        __syncthreads();
        const float csa = a ? cs1 : cs0;
        #pragma unroll
        for (int it = 0; it < 4; ++it) {
            const int m = it * 8 + ms;
            const int r = m + 4;
            const int g = m + 8;
            const float di = sm.dinvs[r][a];
            float v = sm.facs[r][a] * sm.Gs[g][c];
            #pragma unroll
            for (int tt = 0; tt < 8; ++tt) {
                const int off = (tt < 4) ? (tt - 4) : (tt - 3);
                v += di * sm.ps[r + off][7 - tt][a] * sm.ps[r][tt][a]
                        * sm.dinvs[r + off][a] * sm.Gs[g + off][c];
            }
            const float x = csa * v;
            accY += (x > 0.f) ? x : expm1f(x);
        }
        __syncthreads();
    }

    sm.red[t] = accY;
    __syncthreads();

    if (gridDim.x > 1) {
        if (t < 64) {
            float s = 0.f;
            #pragma unroll
            for (int g2 = 0; g2 < 16; ++g2) s += sm.red[(g2 << 6) + t];
            ((float*)out)[blockIdx.x * 64 + t] = s;
        }
        return;
    }

    if (t < 64) {
        float s = 0.f;
        #pragma unroll
        for (int g2 = 0; g2 < 16; ++g2) s += sm.red[(g2 << 6) + t];
        sm.pooled[t] = s * (1.f / 8192.f);
    }
    __syncthreads();
    if (t < 128) {
        float acc = ldv<F32>(bc1, t);
        #pragma unroll 8
        for (int k = 0; k < 64; ++k) acc += sm.pooled[k] * ldv<F32>(Wc1, k * 128 + t);
        sm.hid[t] = fmaxf(acc, 0.f);
    }
    __syncthreads();
    if (t < 8) {
        float acc = ldv<F32>(bc2, t);
        #pragma unroll 8
        for (int k = 0; k < 128; ++k) acc += sm.hid[k] * ldv<F32>(Wc2, k * 8 + t);
        if constexpr (F32) ((float*)out)[t] = acc;
        else ((__hip_bfloat16*)out)[t] = __float2bfloat16(acc);
    }
}

// ---------- K1: node GEMVs, no redundancy ----------
template <bool F32>
static __device__ void k1body(float (*efs)[128], float (*Hs)[64],
    const void* ef, const void* We, const void* be, const void* M1w,
    const void* W2, float* A, float* B, float* G)
{
    const int t = threadIdx.x, c = t & 63, w = t >> 6;
    const int i = blockIdx.x * 16 + w;            // node, one wave per node
    if constexpr (F32) {
        const float* efp = (const float*)ef + i * 128;
        efs[w][2 * c]     = efp[2 * c];
        efs[w][2 * c + 1] = efp[2 * c + 1];
    } else {
        const unsigned int u = ((const unsigned int*)ef)[i * 64 + c];
        efs[w][2 * c]     = __uint_as_float((u & 0xFFFFu) << 16);
        efs[w][2 * c + 1] = __uint_as_float(u & 0xFFFF0000u);
    }
    __syncthreads();
    float aA = 0.f, aB = 0.f, aH = ldv<F32>(be, c);
    #pragma unroll 8
    for (int k = 0; k < 128; ++k) {
        const float ev = efs[w][k];
        aA += ev * ldv<F32>(M1w, k * 64 + c);
        aB += ev * ldv<F32>(M1w, 8192 + k * 64 + c);
        aH += ev * ldv<F32>(We, k * 64 + c);
    }
    A[i * 64 + c] = aA;
    B[i * 64 + c] = aB;
    Hs[w][c] = fmaxf(aH, 0.f);
    __syncthreads();
    float aG = 0.f;
    #pragma unroll 8
    for (int k = 0; k < 64; ++k) aG += Hs[w][k] * ldv<F32>(W2, k * 64 + c);
    G[i * 64 + c] = aG;
}

__global__ __launch_bounds__(1024) void sheaf_k1(
    const void* ef, const void* We, const void* be, const void* M1w,
    const void* W2, float* A, float* B, float* G)
{
    __shared__ float efs[16][128];
    __shared__ float Hs[16][64];
    __shared__ int flag;
    const int t = threadIdx.x;
    if (t == 0) flag = 0;
    __syncthreads();
    {
        const __hip_bfloat16* efh = (const __hip_bfloat16*)ef;
        bool big = false;
        #pragma unroll
        for (int k = 0; k < 8; ++k) {
            const float v = __bfloat162float(efh[t * 8 + k]);
            big |= !(fabsf(v) < 1e4f);
        }
        if (big) atomicOr(&flag, 1);
    }
    __syncthreads();
    if (flag) k1body<true >(efs, Hs, ef, We, be, M1w, W2, A, B, G);
    else      k1body<false>(efs, Hs, ef, We, be, M1w, W2, A, B, G);
}

// ---------- K2: sheaf stencil phases 2-4 ----------
template <bool F32>
static __device__ void k2body(SmemK2& sm,
    const void* M1b, const void* M2w, const void* M2b, const void* W1,
    const float* A, const float* B, const float* G, float* partials)
{
    const int t = threadIdx.x, c = t & 63, w = t >> 6;
    const int base = blockIdx.x * 16;

    // stage halo rows from d_ws
    for (int idx = t; idx < PEXT2 * 64; idx += 1024) {
        const int r = idx >> 6, cc = idx & 63;
        sm.As[r][cc] = A[(((base - 4 + r) & (NN - 1)) << 6) + cc];
    }
    for (int idx = t; idx < 32 * 64; idx += 1024) {
        const int r = idx >> 6, cc = idx & 63;
        const int gi = ((base - 8 + r) & (NN - 1)) << 6;
        sm.Bs[r][cc] = B[gi + cc];
        sm.Gs[r][cc] = G[gi + cc];
    }
    __syncthreads();

    const float m1b_c = ldv<F32>(M1b, c);
    const float m2w0  = ldv<F32>(M2w, c * 2 + 0);
    const float m2w1  = ldv<F32>(M2w, c * 2 + 1);
    const float m2b0  = ldv<F32>(M2b, 0);
    const float m2b1  = ldv<F32>(M2b, 1);
    const float cs0 = ldv<F32>(W1, 0) + ldv<F32>(W1, 2);
    const float cs1 = ldv<F32>(W1, 1) + ldv<F32>(W1, 3);

    // phase 2: p(r,tt), r in [0,24) local (node base-4+r)
    for (int pi = w; pi < PEXT2 * 8; pi += 16) {
        const int r  = pi >> 3;
        const int tt = pi & 7;
        const int off = (tt < 4) ? (tt - 4) : (tt - 3);
        const float h = fmaxf(sm.As[r][c] + sm.Bs[r + 4 + off][c] + m1b_c, 0.f);
        float q0 = h * m2w0, q1 = h * m2w1;
        #pragma unroll
        for (int d2 = 32; d2; d2 >>= 1) {
            q0 += __shfl_xor(q0, d2);
            q1 += __shfl_xor(q1, d2);
        }
        if (c == 0) {
            sm.ps[r][tt][0] = q0 + m2b0;
            sm.ps[r][tt][1] = q1 + m2b1;
        }
    }
    __syncthreads();

    // phase 3
    if (t < PEXT2 * 2) {
        const int r = t >> 1, aa = t & 1;
        float s = 0.f;
        #pragma unroll
        for (int tt = 0; tt < 8; ++tt) { const float p = sm.ps[r][tt][aa]; s += p * p; }
        const float dv = 1.f / sqrtf(fmaxf(s + 1e-5f, 1e-6f));
        sm.dinvs[r][aa] = dv;
        sm.facs[r][aa]  = 1.f - dv * dv * s;
    }
    __syncthreads();

    // phase 4: 16 owned nodes
    float accY = 0.f;
    #pragma unroll
    for (int it = 0; it < 2; ++it) {
        const int m = it * 8 + (t >> 7);
        const int a = (t >> 6) & 1;
        const int r = m + 4;
        const int g = m + 8;
        const float csa = a ? cs1 : cs0;
        const float di = sm.dinvs[r][a];
        float v = sm.facs[r][a] * sm.Gs[g][c];
        #pragma unroll
        for (int tt = 0; tt < 8; ++tt) {
            const int off = (tt < 4) ? (tt - 4) : (tt - 3);
            v += di * sm.ps[r + off][7 - tt][a] * sm.ps[r][tt][a]
                    * sm.dinvs[r + off][a] * sm.Gs[g + off][c];
        }
        const float x = csa * v;
        accY += (x > 0.f) ? x : expm1f(x);
    }

    sm.red[t] = accY;
    __syncthreads();
    if (t < 64) {
        float s = 0.f;
        #pragma unroll
        for (int g2 = 0; g2 < 16; ++g2) s += sm.red[(g2 << 6) + t];
        partials[blockIdx.x * 64 + t] = s;
    }
}

__global__ __launch_bounds__(1024) void sheaf_k2(
    const void* ef, const void* M1b, const void* M2w, const void* M2b,
    const void* W1, const float* A, const float* B, const float* G,
    float* partials)
{
    __shared__ SmemK2 sm;
    __shared__ int flag;
    const int t = threadIdx.x;
    if (t == 0) flag = 0;
    __syncthreads();
    {
        const __hip_bfloat16* efh = (const __hip_bfloat16*)ef;
        bool big = false;
        #pragma unroll
        for (int k = 0; k < 8; ++k) {
            const float v = __bfloat162float(efh[t * 8 + k]);
            big |= !(fabsf(v) < 1e4f);
        }
        if (big) atomicOr(&flag, 1);
    }
    __syncthreads();
    if (flag) k2body<true >(sm, M1b, M2w, M2b, W1, A, B, G, partials);
    else      k2body<false>(sm, M1b, M2w, M2b, W1, A, B, G, partials);
}

// Trivial canary: if ANY kernel can execute, out[0..7] become ~1.0.
__global__ __launch_bounds__(64) void sheaf_canary(unsigned short* out)
{
    if (threadIdx.x < 8) out[threadIdx.x] = 0x3F80;
}

// Finalize: fixed-order reduce of nparts partials + classifier -> out.
__global__ __launch_bounds__(256) void sheaf_finalize(
    const void* ef, const void* Wc1, const void* bc1, const void* Wc2,
    const void* bc2, const float* partials, int nparts, void* out)
{
    __shared__ float red[256];
    __shared__ float pooled[64];
    __shared__ float hid[128];
    __shared__ int flag;
    const int t = threadIdx.x;
    if (t == 0) flag = 0;
    __syncthreads();
    {
        const __hip_bfloat16* efh = (const __hip_bfloat16*)ef;
        bool big = false;
        #pragma unroll
        for (int k = 0; k < 8; ++k) {
            const float v = __bfloat162float(efh[t * 8 + k]);
            big |= !(fabsf(v) < 1e4f);
        }
        if (big) atomicOr(&flag, 1);
    }
    __syncthreads();
    const bool f32 = (flag != 0);

    const int h = t & 63, g = t >> 6;
    float s = 0.f;
    for (int b = g; b < nparts; b += 4) s += partials[b * 64 + h];
    red[t] = s;
    __syncthreads();
    if (t < 64)
        pooled[t] = (red[t] + red[t + 64] + red[t + 128] + red[t + 192]) * (1.f / 8192.f);
    __syncthreads();
    if (t < 128) {
        float acc = ldr(bc1, t, f32);
        #pragma unroll 8
        for (int k = 0; k < 64; ++k) acc += pooled[k] * ldr(Wc1, k * 128 + t, f32);
        hid[t] = fmaxf(acc, 0.f);
    }
    __syncthreads();
    if (t < 8) {
        float acc = ldr(bc2, t, f32);
        #pragma unroll 8
        for (int k = 0; k < 128; ++k) acc += hid[k] * ldr(Wc2, k * 8 + t, f32);
        if (f32) ((float*)out)[t] = acc;
        else ((__hip_bfloat16*)out)[t] = __float2bfloat16(acc);
    }
}

__global__ __launch_bounds__(1024) void SheafConvolutionalNetwork_81698867905240_kernel(
    const void* ef, const void* We, const void* be, const void* M1w,
    const void* M1b, const void* M2w, const void* M2b, const void* W1,
    const void* W2, const void* Wc1, const void* bc1, const void* Wc2,
    const void* bc2, void* out)
{
    __shared__ Smem sm;
    __shared__ int flag;
    const int t = threadIdx.x;
    if (t == 0) flag = 0;
    __syncthreads();
    {
        const __hip_bfloat16* efh = (const __hip_bfloat16*)ef;
        bool big = false;
        #pragma unroll
        for (int k = 0; k < 8; ++k) {
            const float v = __bfloat162float(efh[t * 8 + k]);
            big |= !(fabsf(v) < 1e4f);
        }
        if (big) atomicOr(&flag, 1);
    }
    __syncthreads();
    if (flag)
        body<true >(sm, ef, We, be, M1w, M1b, M2w, M2b, W1, W2, Wc1, bc1, Wc2, bc2, out);
    else
        body<false>(sm, ef, We, be, M1w, M1b, M2w, M2b, W1, W2, Wc1, bc1, Wc2, bc2, out);
}

extern "C" void kernel_launch(void* const* d_in, const int* in_sizes, int n_in,
                              void* d_out, int out_size, void* d_ws, size_t ws_size,
                              hipStream_t stream)
{
    (void)in_sizes; (void)n_in; (void)out_size;

    // Fingerprint 1: stream memset marks d_out (~0.747 in both dtypes).
    (void)hipMemsetAsync(d_out, 0x3F, 16, stream);
    // Fingerprint 2: trivial canary kernel (~1.0 in both dtypes).
    sheaf_canary<<<dim3(1), dim3(64), 0, stream>>>((unsigned short*)d_out);
    (void)hipGetLastError();

    if (d_ws != nullptr && ws_size >= (size_t)WS_PIPE) {
        float* A = (float*)d_ws;
        float* B = A + NN * 64;
        float* G = B + NN * 64;
        float* partials = G + NN * 64;
        sheaf_k1<<<dim3(NBLK2), dim3(1024), 0, stream>>>(
            d_in[0], d_in[1], d_in[2], d_in[3], d_in[8], A, B, G);
        sheaf_k2<<<dim3(NBLK2), dim3(1024), 0, stream>>>(
            d_in[0], d_in[4], d_in[5], d_in[6], d_in[7], A, B, G, partials);
        sheaf_finalize<<<dim3(1), dim3(256), 0, stream>>>(
            d_in[0], d_in[9], d_in[10], d_in[11], d_in[12],
            partials, NBLK2, d_out);
    } else if (d_ws != nullptr && ws_size >= (size_t)WS_R17) {
        // R17-proven fallback: 128-block halo kernel + finalize
        SheafConvolutionalNetwork_81698867905240_kernel<<<dim3(NGRID), dim3(1024), 0, stream>>>(
            d_in[0], d_in[1], d_in[2], d_in[3], d_in[4], d_in[5], d_in[6],
            d_in[7], d_in[8], d_in[9], d_in[10], d_in[11], d_in[12], d_ws);
        sheaf_finalize<<<dim3(1), dim3(256), 0, stream>>>(
            d_in[0], d_in[9], d_in[10], d_in[11], d_in[12],
            (const float*)d_ws, NGRID, d_out);
    } else {
        // R8-proven fallback: single block direct to d_out
        SheafConvolutionalNetwork_81698867905240_kernel<<<dim3(1), dim3(1024), 0, stream>>>(
            d_in[0], d_in[1], d_in[2], d_in[3], d_in[4], d_in[5], d_in[6],
            d_in[7], d_in[8], d_in[9], d_in[10], d_in[11], d_in[12], d_out);
    }

    // Fingerprint 3: explicit launch-error marker (~12.06 in both dtypes).
    if (hipGetLastError() != hipSuccess)
        (void)hipMemsetAsync(d_out, 0x41, 16, stream);
}